// Round 3
// baseline (244.747 us; speedup 1.0000x reference)
//
#include <hip/hip_runtime.h>

#define SEQ 200
#define HID 64
#define BT  4
#define NBLK (4096 / BT)   // 1024 blocks -> 4 per CU

typedef _Float16 f16;
typedef _Float16 f16x8 __attribute__((ext_vector_type(8)));
typedef float    f32x4 __attribute__((ext_vector_type(4)));

__device__ __forceinline__ float sigmoid_f(float x) {
    return 1.0f / (1.0f + __expf(-x));
}
__device__ __forceinline__ float tanh_f(float x) {
    // tanh(x) = 1 - 2/(exp(2x)+1); saturates correctly, no NaN
    float e = __expf(2.0f * x);
    return 1.0f - 2.0f / (e + 1.0f);
}

// 4 batch rows per block, 4 blocks/CU for latency hiding.
// Per step: gate GEMM C[16x256] = h[16x64]_f16 @ W_hh^T (rows 4..15 of h are zero)
// on MFMA; raw gates exchanged via LDS so the pointwise LSTM cell runs FULL-LANE:
// thread (wave w, lane l) owns exactly one cell (b=w, j=l).
__global__ __launch_bounds__(256, 4)
void qlstm_mfma4(const float* __restrict__ x,      // [4096, 200]
                 const float* __restrict__ W_ih,   // [256]
                 const float* __restrict__ W_hh,   // [256, 64]
                 const float* __restrict__ b_ih,   // [256]
                 const float* __restrict__ b_hh,   // [256]
                 const float* __restrict__ W_lin,  // [200*64]
                 const float* __restrict__ b_lin,  // [1]
                 float* __restrict__ out)          // [4096]
{
    __shared__ f16   x_lds[16 * 201];          // rows >= BT stay zero; pad 201
    __shared__ f16   h_frag[16 * HID];         // 2 KB, A-frag order, XOR-swizzled 16B slots
    __shared__ float gates_lds[BT][HID][4];    // [b][j][q] raw gates, 4 KB

    const int tid = threadIdx.x;
    const int w   = tid >> 6;     // wave: j-block owner (gate phase) / batch row (pointwise)
    const int l   = tid & 63;
    const int m   = l & 15;       // A row / B col
    const int a   = l >> 4;       // k-block / C row-group
    const int b0  = blockIdx.x * BT;

    // ---- stage x rows 0..BT-1 as f16 ----
    for (int i = tid; i < BT * SEQ; i += 256) {
        int b = i / SEQ;
        int t = i - b * SEQ;
        x_lds[b * 201 + t] = (f16)x[(size_t)b0 * SEQ + i];
    }
    // zero rows BT..15 (incl. pads)
    for (int i = BT * 201 + tid; i < 16 * 201; i += 256) x_lds[i] = (f16)0.0f;
    // zero h fragment buffer (h0 = 0; rows BT..15 stay zero forever)
    for (int i = tid; i < (16 * HID) / 2; i += 256) ((float*)h_frag)[i] = 0.0f;

    // ---- B fragments (W_hh^T) into registers, once ----
    // B[k][n] = W_hh[n][k]; lane holds k = kk*32 + 8*a + e (contiguous), n = 16w + m.
    f16x8 Bf[4][2];
    float biasq[4], wihq[4];
    #pragma unroll
    for (int q = 0; q < 4; ++q) {
        const int n = q * 64 + w * 16 + m;
        biasq[q] = b_ih[n] + b_hh[n];
        wihq[q]  = W_ih[n];
        #pragma unroll
        for (int kk = 0; kk < 2; ++kk) {
            const float4* p = (const float4*)(W_hh + n * HID + kk * 32 + a * 8);
            float4 lo = p[0], hi = p[1];
            f16x8 f;
            f[0] = (f16)lo.x; f[1] = (f16)lo.y; f[2] = (f16)lo.z; f[3] = (f16)lo.w;
            f[4] = (f16)hi.x; f[5] = (f16)hi.y; f[6] = (f16)hi.z; f[7] = (f16)hi.w;
            Bf[q][kk] = f;
        }
    }

    const int jj = w * 16 + m;
    // A-frag read addrs: row m, slot s = kk*4 + a, byte = m*128 + ((s ^ (m&7))<<4)
    const int ra0 = m * 128 + (((0 + a) ^ (m & 7)) << 4);
    const int ra1 = m * 128 + (((4 + a) ^ (m & 7)) << 4);
    // pointwise h-write addr for cell (b=w, j=l):
    // byte = b*128 + (((j>>3) ^ (b&7))<<4) + (j&7)*2
    const int hwa = w * 128 + ((((l >> 3)) ^ (w & 7)) << 4) + (l & 7) * 2;

    float c_state = 0.0f;
    float out_acc = 0.0f;

    __syncthreads();

    for (int t = 0; t < SEQ; ++t) {
        // ======== gate phase (MFMA) ========
        const f16x8 A0 = *(const f16x8*)((const char*)h_frag + ra0);
        const f16x8 A1 = *(const f16x8*)((const char*)h_frag + ra1);
        float xr[4];
        #pragma unroll
        for (int r = 0; r < 4; ++r) xr[r] = (float)x_lds[(4 * a + r) * 201 + t];

        f32x4 acc[4];
        #pragma unroll
        for (int q = 0; q < 4; ++q) {
            f32x4 ini;
            #pragma unroll
            for (int r = 0; r < 4; ++r) ini[r] = fmaf(xr[r], wihq[q], biasq[q]);
            ini    = __builtin_amdgcn_mfma_f32_16x16x32_f16(A0, Bf[q][0], ini, 0, 0, 0);
            acc[q] = __builtin_amdgcn_mfma_f32_16x16x32_f16(A1, Bf[q][1], ini, 0, 0, 0);
        }

        // scatter raw gates for valid rows (a == 0 holds rows 0..3 = b)
        if (a == 0) {
            #pragma unroll
            for (int r = 0; r < 4; ++r) {
                float4 g = make_float4(acc[0][r], acc[1][r], acc[2][r], acc[3][r]);
                *(float4*)&gates_lds[r][jj][0] = g;
            }
        }

        __syncthreads();   // gates visible; h_frag reads of this step done

        // ======== pointwise phase: one cell per thread (b=w, j=l) ========
        const float wl = W_lin[t * HID + l];   // 256B/wave, L1-resident
        const float4 g = *(const float4*)&gates_lds[w][l][0];
        const float ig = sigmoid_f(g.x);
        const float fg = sigmoid_f(g.y);
        const float gg = tanh_f(g.z);
        const float og = sigmoid_f(g.w);
        c_state = fmaf(fg, c_state, ig * gg);
        const float h = og * tanh_f(c_state);
        out_acc = fmaf(h, wl, out_acc);
        *(f16*)((char*)h_frag + hwa) = (f16)h;

        __syncthreads();   // h writes visible before next gate phase
    }

    // ---- reduce out_acc over j (64 lanes) ----
    float v = out_acc;
    #pragma unroll
    for (int off = 32; off > 0; off >>= 1)
        v += __shfl_down(v, off, 64);
    if (l == 0)
        out[b0 + w] = v + b_lin[0];
}

extern "C" void kernel_launch(void* const* d_in, const int* in_sizes, int n_in,
                              void* d_out, int out_size, void* d_ws, size_t ws_size,
                              hipStream_t stream) {
    const float* x     = (const float*)d_in[0];
    const float* W_ih  = (const float*)d_in[1];
    const float* W_hh  = (const float*)d_in[2];
    const float* b_ih  = (const float*)d_in[3];
    const float* b_hh  = (const float*)d_in[4];
    const float* W_lin = (const float*)d_in[5];
    const float* b_lin = (const float*)d_in[6];
    float* out = (float*)d_out;

    dim3 grid(NBLK);
    dim3 block(256);
    qlstm_mfma4<<<grid, block, 0, stream>>>(x, W_ih, W_hh, b_ih, b_hh,
                                            W_lin, b_lin, out);
}

// Round 4
// 212.452 us; speedup vs baseline: 1.1520x; 1.1520x over previous
//
#include <hip/hip_runtime.h>

#define SEQ 200
#define HID 64
#define BT  4
#define NBLK (4096 / BT)   // 1024 blocks -> 4 per CU

typedef _Float16 f16;
typedef _Float16 f16x8 __attribute__((ext_vector_type(8)));
typedef float    f32x4 __attribute__((ext_vector_type(4)));

__device__ __forceinline__ float sigmoid_f(float x) {
    return 1.0f / (1.0f + __expf(-x));
}
__device__ __forceinline__ float tanh_f(float x) {
    // tanh(x) = 1 - 2/(exp(2x)+1); saturates correctly, no NaN
    float e = __expf(2.0f * x);
    return 1.0f - 2.0f / (e + 1.0f);
}

// BT=4 rows/block, 1024 blocks (4/CU). ONE barrier per step:
//  - gate GEMM: wave w computes ALL 4 quadrants for j-cols [16w,16w+16)
//    (8 MFMAs, C rows 0..3 valid), so gates never cross waves.
//  - in-wave redistribute of C-fragments through wave-private LDS (no barrier;
//    same-wave DS ops are program-ordered).
//  - pointwise full-lane: thread (w,l) owns cell (b = l>>4, j = 16w + (l&15)).
//  - h double-buffered in LDS (A-fragment layout, XOR-swizzled 16B slots):
//    read buf (t&1), write buf (t&1)^1, single __syncthreads at step end.
__global__ __launch_bounds__(256, 4)
void qlstm_v4(const float* __restrict__ x,      // [4096, 200]
              const float* __restrict__ W_ih,   // [256]
              const float* __restrict__ W_hh,   // [256, 64]
              const float* __restrict__ b_ih,   // [256]
              const float* __restrict__ b_hh,   // [256]
              const float* __restrict__ W_lin,  // [200*64]
              const float* __restrict__ b_lin,  // [1]
              float* __restrict__ out)          // [4096]
{
    __shared__ float x_lds[BT][SEQ];            // 3.2 KB
    __shared__ f16   h_frag[2][16 * HID];       // 4 KB, dbuf, swizzled frag layout
    __shared__ float gates_lds[4][4][16][4];    // [wave][r][m][q], wave-private 1KB each
    __shared__ float out_part[4][BT];

    const int tid = threadIdx.x;
    const int w   = tid >> 6;     // wave: j-block owner
    const int l   = tid & 63;
    const int m   = l & 15;       // B col / C col
    const int a   = l >> 4;       // k-group (A/B frags); batch row in pointwise
    const int b0  = blockIdx.x * BT;

    // ---- stage x rows 0..3 (f32, coalesced) ----
    for (int i = tid; i < BT * SEQ; i += 256) {
        int b = i / SEQ, t = i - b * SEQ;
        x_lds[b][t] = x[(size_t)b0 * SEQ + i];
    }
    // ---- zero both h buffers (rows 4..15 stay zero forever) ----
    for (int i = tid; i < 1024; i += 256) ((float*)h_frag)[i] = 0.0f;

    // ---- B fragments (W_hh^T) once: lane holds col n=q*64+16w+m, k=kk*32+a*8+e ----
    f16x8 Bf[4][2];
    #pragma unroll
    for (int q = 0; q < 4; ++q) {
        const int n = q * 64 + w * 16 + m;
        #pragma unroll
        for (int kk = 0; kk < 2; ++kk) {
            const float4* p = (const float4*)(W_hh + n * HID + kk * 32 + a * 8);
            float4 lo = p[0], hi = p[1];
            f16x8 f;
            f[0] = (f16)lo.x; f[1] = (f16)lo.y; f[2] = (f16)lo.z; f[3] = (f16)lo.w;
            f[4] = (f16)hi.x; f[5] = (f16)hi.y; f[6] = (f16)hi.z; f[7] = (f16)hi.w;
            Bf[q][kk] = f;
        }
    }

    // ---- pointwise per-thread constants: cell (b=a, j=jpw) ----
    const int jpw = w * 16 + m;
    float wihp[4], biasp[4];
    #pragma unroll
    for (int q = 0; q < 4; ++q) {
        const int n = q * 64 + jpw;
        wihp[q]  = W_ih[n];
        biasp[q] = b_ih[n] + b_hh[n];
    }

    const char* hbytes = (const char*)h_frag;
    // A-frag read addrs: row m, slot s=kk*4+a, byte = m*128 + ((s^(m&7))<<4)
    const int ra0 = m * 128 + (((0 + a) ^ (m & 7)) << 4);
    const int ra1 = m * 128 + (((4 + a) ^ (m & 7)) << 4);
    // h write addr for cell (b=a, j=jpw): byte = b*128 + (((j>>3)^b)<<4) + (j&7)*2
    const int hwa = a * 128 + (((jpw >> 3) ^ a) << 4) + (jpw & 7) * 2;

    float c_state = 0.0f, out_acc = 0.0f;

    __syncthreads();

    for (int t = 0; t < SEQ; ++t) {
        const int rb = (t & 1) << 11;                 // read-buffer byte offset
        const float wl = W_lin[t * HID + jpw];        // issued early, used late

        // ======== gate GEMM ========
        const f16x8 A0 = *(const f16x8*)(hbytes + rb + ra0);
        const f16x8 A1 = *(const f16x8*)(hbytes + rb + ra1);

        f32x4 acc[4];
        #pragma unroll
        for (int q = 0; q < 4; ++q) {
            f32x4 z = {0.f, 0.f, 0.f, 0.f};
            z      = __builtin_amdgcn_mfma_f32_16x16x32_f16(A0, Bf[q][0], z, 0, 0, 0);
            acc[q] = __builtin_amdgcn_mfma_f32_16x16x32_f16(A1, Bf[q][1], z, 0, 0, 0);
        }

        // ---- in-wave redistribute (wave-private region, no barrier) ----
        if (a == 0) {
            #pragma unroll
            for (int r = 0; r < 4; ++r)
                *(float4*)&gates_lds[w][r][m][0] =
                    make_float4(acc[0][r], acc[1][r], acc[2][r], acc[3][r]);
        }
        __builtin_amdgcn_wave_barrier();   // compile-time order pin (HW is in-order)
        const float4 g = *(const float4*)&gates_lds[w][a][m][0];

        // ======== pointwise: one cell per thread ========
        const float xv = x_lds[a][t];
        const float gi = sigmoid_f(g.x + fmaf(xv, wihp[0], biasp[0]));
        const float gf = sigmoid_f(g.y + fmaf(xv, wihp[1], biasp[1]));
        const float gg = tanh_f   (g.z + fmaf(xv, wihp[2], biasp[2]));
        const float go = sigmoid_f(g.w + fmaf(xv, wihp[3], biasp[3]));
        c_state = fmaf(gf, c_state, gi * gg);
        const float h = go * tanh_f(c_state);
        out_acc = fmaf(h, wl, out_acc);
        *(f16*)((char*)h_frag + (rb ^ 2048) + hwa) = (f16)h;

        __syncthreads();   // h(write-buf) complete -> next step reads it
    }

    // ---- reduce out_acc over j: 16 lanes (m) in-wave, then 4 waves via LDS ----
    float v = out_acc;
    v += __shfl_xor(v, 1, 64);
    v += __shfl_xor(v, 2, 64);
    v += __shfl_xor(v, 4, 64);
    v += __shfl_xor(v, 8, 64);
    if (m == 0) out_part[w][a] = v;
    __syncthreads();
    if (tid < BT) {
        out[b0 + tid] = out_part[0][tid] + out_part[1][tid]
                      + out_part[2][tid] + out_part[3][tid] + b_lin[0];
    }
}

extern "C" void kernel_launch(void* const* d_in, const int* in_sizes, int n_in,
                              void* d_out, int out_size, void* d_ws, size_t ws_size,
                              hipStream_t stream) {
    const float* x     = (const float*)d_in[0];
    const float* W_ih  = (const float*)d_in[1];
    const float* W_hh  = (const float*)d_in[2];
    const float* b_ih  = (const float*)d_in[3];
    const float* b_hh  = (const float*)d_in[4];
    const float* W_lin = (const float*)d_in[5];
    const float* b_lin = (const float*)d_in[6];
    float* out = (float*)d_out;

    dim3 grid(NBLK);
    dim3 block(256);
    qlstm_v4<<<grid, block, 0, stream>>>(x, W_ih, W_hh, b_ih, b_hh,
                                         W_lin, b_lin, out);
}

// Round 5
// 167.360 us; speedup vs baseline: 1.4624x; 1.2694x over previous
//
#include <hip/hip_runtime.h>

#define SEQ 200
#define HID 64
#define BT  4
#define NBLK (4096 / BT)   // 1024 blocks -> 4 per CU

typedef _Float16 f16;
typedef _Float16 f16x8 __attribute__((ext_vector_type(8)));
typedef float    f32x4 __attribute__((ext_vector_type(4)));

#define LOG2E  1.44269504088896340736f

#if __has_builtin(__builtin_amdgcn_exp2f)
#define EXP2F(x) __builtin_amdgcn_exp2f(x)
#else
#define EXP2F(x) __expf(0.69314718056f * (x))
#endif
#define RCPF(x) __builtin_amdgcn_rcpf(x)

// Gate pre-activations arrive PRE-SCALED: i/f/o by log2e, g by 2*log2e
// (folded into W_hh/W_ih/bias at load time).
//   sigmoid(raw) = rcp(1 + 2^(-s))            , s = log2e * raw
//   tanh(raw)    = 1 - 2*rcp(2^(s2) + 1)      , s2 = 2*log2e * raw
__device__ __forceinline__ float sigmoid_s(float s) {
    return RCPF(1.0f + EXP2F(-s));
}
__device__ __forceinline__ float tanh_s2(float s2) {
    return fmaf(-2.0f, RCPF(1.0f + EXP2F(s2)), 1.0f);
}

// BT=4 rows/block, 1024 blocks (4/CU). ONE barrier per step:
//  - gate GEMM: wave w computes ALL 4 quadrants for j-cols [16w,16w+16)
//    (8 MFMAs, C rows 0..3 valid), so gates never cross waves.
//  - in-wave redistribute of C-fragments through wave-private LDS (no barrier).
//  - pointwise full-lane: thread (w,l) owns cell (b = l>>4, j = 16w + (l&15)).
//  - h double-buffered in LDS (A-fragment layout, XOR-swizzled 16B slots).
__global__ __launch_bounds__(256, 4)
void qlstm_v5(const float* __restrict__ x,      // [4096, 200]
              const float* __restrict__ W_ih,   // [256]
              const float* __restrict__ W_hh,   // [256, 64]
              const float* __restrict__ b_ih,   // [256]
              const float* __restrict__ b_hh,   // [256]
              const float* __restrict__ W_lin,  // [200*64]
              const float* __restrict__ b_lin,  // [1]
              float* __restrict__ out)          // [4096]
{
    __shared__ float x_lds[BT][SEQ];            // 3.2 KB
    __shared__ f16   h_frag[2][16 * HID];       // 4 KB, dbuf, swizzled frag layout
    __shared__ float gates_lds[4][4][16][4];    // [wave][r][m][q], wave-private 1KB each
    __shared__ float out_part[4][BT];

    const int tid = threadIdx.x;
    const int w   = tid >> 6;     // wave: j-block owner
    const int l   = tid & 63;
    const int m   = l & 15;       // B col / C col
    const int a   = l >> 4;       // k-group (A/B frags); batch row in pointwise
    const int b0  = blockIdx.x * BT;

    // quadrant pre-scales: i,f,o -> log2e ; g -> 2*log2e
    const float qs[4] = {LOG2E, LOG2E, 2.0f * LOG2E, LOG2E};

    // ---- stage x rows 0..3 (f32, coalesced) ----
    for (int i = tid; i < BT * SEQ; i += 256) {
        int b = i / SEQ, t = i - b * SEQ;
        x_lds[b][t] = x[(size_t)b0 * SEQ + i];
    }
    // ---- zero both h buffers (rows 4..15 stay zero forever) ----
    for (int i = tid; i < 1024; i += 256) ((float*)h_frag)[i] = 0.0f;

    // ---- B fragments (W_hh^T, pre-scaled) once: col n=q*64+16w+m, k=kk*32+a*8+e ----
    f16x8 Bf[4][2];
    #pragma unroll
    for (int q = 0; q < 4; ++q) {
        const int n = q * 64 + w * 16 + m;
        #pragma unroll
        for (int kk = 0; kk < 2; ++kk) {
            const float4* p = (const float4*)(W_hh + n * HID + kk * 32 + a * 8);
            float4 lo = p[0], hi = p[1];
            f16x8 f;
            f[0] = (f16)(lo.x * qs[q]); f[1] = (f16)(lo.y * qs[q]);
            f[2] = (f16)(lo.z * qs[q]); f[3] = (f16)(lo.w * qs[q]);
            f[4] = (f16)(hi.x * qs[q]); f[5] = (f16)(hi.y * qs[q]);
            f[6] = (f16)(hi.z * qs[q]); f[7] = (f16)(hi.w * qs[q]);
            Bf[q][kk] = f;
        }
    }

    // ---- pointwise per-thread constants (pre-scaled): cell (b=a, j=jpw) ----
    const int jpw = w * 16 + m;
    float wihp[4], biasp[4];
    #pragma unroll
    for (int q = 0; q < 4; ++q) {
        const int n = q * 64 + jpw;
        wihp[q]  = W_ih[n] * qs[q];
        biasp[q] = (b_ih[n] + b_hh[n]) * qs[q];
    }

    const char* hbytes = (const char*)h_frag;
    // A-frag read addrs: row m, slot s=kk*4+a, byte = m*128 + ((s^(m&7))<<4)
    const int ra0 = m * 128 + (((0 + a) ^ (m & 7)) << 4);
    const int ra1 = m * 128 + (((4 + a) ^ (m & 7)) << 4);
    // h write addr for cell (b=a, j=jpw): byte = b*128 + (((j>>3)^b)<<4) + (j&7)*2
    const int hwa = a * 128 + (((jpw >> 3) ^ a) << 4) + (jpw & 7) * 2;

    float c_state = 0.0f, out_acc = 0.0f;

    __syncthreads();

    for (int t = 0; t < SEQ; ++t) {
        const int rb = (t & 1) << 11;                 // read-buffer byte offset
        const float wl = W_lin[t * HID + jpw];        // issued early, used late

        // ======== gate GEMM ========
        const f16x8 A0 = *(const f16x8*)(hbytes + rb + ra0);
        const f16x8 A1 = *(const f16x8*)(hbytes + rb + ra1);

        f32x4 acc[4];
        #pragma unroll
        for (int q = 0; q < 4; ++q) {
            f32x4 z = {0.f, 0.f, 0.f, 0.f};
            z      = __builtin_amdgcn_mfma_f32_16x16x32_f16(A0, Bf[q][0], z, 0, 0, 0);
            acc[q] = __builtin_amdgcn_mfma_f32_16x16x32_f16(A1, Bf[q][1], z, 0, 0, 0);
        }

        // ---- in-wave redistribute (wave-private region, no barrier) ----
        if (a == 0) {
            #pragma unroll
            for (int r = 0; r < 4; ++r)
                *(float4*)&gates_lds[w][r][m][0] =
                    make_float4(acc[0][r], acc[1][r], acc[2][r], acc[3][r]);
        }
        __builtin_amdgcn_wave_barrier();   // order pin (same-wave DS ops are in-order)
        const float4 g = *(const float4*)&gates_lds[w][a][m][0];

        // ======== pointwise: one cell per thread (pre-scaled domain) ========
        const float xv = x_lds[a][t];
        const float gi = sigmoid_s(g.x + fmaf(xv, wihp[0], biasp[0]));
        const float gf = sigmoid_s(g.y + fmaf(xv, wihp[1], biasp[1]));
        const float gg = tanh_s2  (g.z + fmaf(xv, wihp[2], biasp[2]));
        const float go = sigmoid_s(g.w + fmaf(xv, wihp[3], biasp[3]));
        c_state = fmaf(gf, c_state, gi * gg);
        const float h = go * tanh_s2((2.0f * LOG2E) * c_state);
        out_acc = fmaf(h, wl, out_acc);
        *(f16*)((char*)h_frag + (rb ^ 2048) + hwa) = (f16)h;

        __syncthreads();   // h(write-buf) complete -> next step reads it
    }

    // ---- reduce out_acc over j: 16 lanes (m) in-wave, then 4 waves via LDS ----
    float v = out_acc;
    v += __shfl_xor(v, 1, 64);
    v += __shfl_xor(v, 2, 64);
    v += __shfl_xor(v, 4, 64);
    v += __shfl_xor(v, 8, 64);
    if (m == 0) out_part[w][a] = v;
    __syncthreads();
    if (tid < BT) {
        out[b0 + tid] = out_part[0][tid] + out_part[1][tid]
                      + out_part[2][tid] + out_part[3][tid] + b_lin[0];
    }
}

extern "C" void kernel_launch(void* const* d_in, const int* in_sizes, int n_in,
                              void* d_out, int out_size, void* d_ws, size_t ws_size,
                              hipStream_t stream) {
    const float* x     = (const float*)d_in[0];
    const float* W_ih  = (const float*)d_in[1];
    const float* W_hh  = (const float*)d_in[2];
    const float* b_ih  = (const float*)d_in[3];
    const float* b_hh  = (const float*)d_in[4];
    const float* W_lin = (const float*)d_in[5];
    const float* b_lin = (const float*)d_in[6];
    float* out = (float*)d_out;

    dim3 grid(NBLK);
    dim3 block(256);
    qlstm_v5<<<grid, block, 0, stream>>>(x, W_ih, W_hh, b_ih, b_hh,
                                         W_lin, b_lin, out);
}

// Round 6
// 128.949 us; speedup vs baseline: 1.8980x; 1.2979x over previous
//
#include <hip/hip_runtime.h>

#define SEQ 200
#define HID 64
#define BT  8
#define NBLK (4096 / BT)   // 512 blocks -> 2 per CU

typedef _Float16 f16;
typedef _Float16 f16x8 __attribute__((ext_vector_type(8)));
typedef float    f32x4 __attribute__((ext_vector_type(4)));

#define LOG2E 1.44269504088896340736f

#if __has_builtin(__builtin_amdgcn_exp2f)
#define EXP2F(x) __builtin_amdgcn_exp2f(x)
#else
#define EXP2F(x) __expf(0.69314718056f * (x))
#endif
#define RCPF(x) __builtin_amdgcn_rcpf(x)

// Pre-scaled domain: i/f/o gates scaled by log2e, g gate by 2*log2e
// (folded into W_hh/W_ih/bias at load time).
__device__ __forceinline__ float sigmoid_s(float s) {
    return RCPF(1.0f + EXP2F(-s));
}
__device__ __forceinline__ float tanh_s2(float s2) {
    return fmaf(-2.0f, RCPF(1.0f + EXP2F(s2)), 1.0f);
}

// BT=8 rows/block, 512 blocks (2/CU, 2 waves/SIMD). One barrier/step, NO LDS
// gate exchange:
//  - wave w owns j-cols [16w,16w+16) for all 4 quadrants: 8 MFMAs, C rows 0..7
//    valid (held natively by lane groups a=0,1).
//  - half-swap via 8 __shfl: lanes a>=2 pull regs r=2,3 from lane l-32 ->
//    every lane runs exactly 2 cells. Cell rows: bA = 4*(a&1)+2*(a>>1), bB=bA+1.
//  - x*W_ih + bias folded into MFMA C-input.
//  - W_lin staged in LDS -> zero VMEM in the loop.
//  - h double-buffered in LDS (A-frag layout, XOR-swizzled 16B slots).
__global__ __launch_bounds__(256, 2)
void qlstm_v6(const float* __restrict__ x,      // [4096, 200]
              const float* __restrict__ W_ih,   // [256]
              const float* __restrict__ W_hh,   // [256, 64]
              const float* __restrict__ b_ih,   // [256]
              const float* __restrict__ b_hh,   // [256]
              const float* __restrict__ W_lin,  // [200*64]
              const float* __restrict__ b_lin,  // [1]
              float* __restrict__ out)          // [4096]
{
    __shared__ float x_lds[16][201];        // 12.9 KB; rows 8..15 zero
    __shared__ f16   h_frag[2][16 * HID];   // 4 KB dbuf, swizzled frag layout
    __shared__ float wl_lds[SEQ * HID];     // 51.2 KB
    __shared__ float out_part[4][BT];

    const int tid = threadIdx.x;
    const int w   = tid >> 6;     // wave: j-block owner
    const int l   = tid & 63;
    const int m   = l & 15;       // B col / C col
    const int a   = l >> 4;       // k-group / C row-group
    const int b0  = blockIdx.x * BT;

    // quadrant pre-scales: i,f,o -> log2e ; g -> 2*log2e
    const float qs[4] = {LOG2E, LOG2E, 2.0f * LOG2E, LOG2E};

    // ---- stage x rows 0..7 (f32, coalesced) ----
    for (int i = tid; i < BT * SEQ; i += 256) {
        int b = i / SEQ, t = i - b * SEQ;
        x_lds[b][t] = x[(size_t)b0 * SEQ + i];
    }
    // ---- zero x rows 8..15 (flat; disjoint from staged rows) ----
    {
        float* z = &x_lds[8][0];
        for (int i = tid; i < 8 * 201; i += 256) z[i] = 0.0f;
    }
    // ---- stage W_lin (float4) ----
    {
        const float4* src = (const float4*)W_lin;
        float4* dst = (float4*)wl_lds;
        for (int i = tid; i < SEQ * HID / 4; i += 256) dst[i] = src[i];
    }
    // ---- zero both h buffers (rows 8..15 stay zero forever) ----
    for (int i = tid; i < 1024; i += 256) ((float*)h_frag)[i] = 0.0f;

    // ---- B fragments (W_hh^T, pre-scaled) once: col n=q*64+16w+m, k=kk*32+a*8+e ----
    f16x8 Bf[4][2];
    float wihq[4], biasq[4];
    #pragma unroll
    for (int q = 0; q < 4; ++q) {
        const int n = q * 64 + w * 16 + m;
        wihq[q]  = W_ih[n] * qs[q];
        biasq[q] = (b_ih[n] + b_hh[n]) * qs[q];
        #pragma unroll
        for (int kk = 0; kk < 2; ++kk) {
            const float4* p = (const float4*)(W_hh + n * HID + kk * 32 + a * 8);
            float4 lo = p[0], hi = p[1];
            f16x8 f;
            f[0] = (f16)(lo.x * qs[q]); f[1] = (f16)(lo.y * qs[q]);
            f[2] = (f16)(lo.z * qs[q]); f[3] = (f16)(lo.w * qs[q]);
            f[4] = (f16)(hi.x * qs[q]); f[5] = (f16)(hi.y * qs[q]);
            f[6] = (f16)(hi.z * qs[q]); f[7] = (f16)(hi.w * qs[q]);
            Bf[q][kk] = f;
        }
    }

    const int jpw = w * 16 + m;
    // A-frag read addrs: row m, slot s=kk*4+a, byte = m*128 + ((s^(m&7))<<4)
    const int ra0 = m * 128 + (((0 + a) ^ (m & 7)) << 4);
    const int ra1 = m * 128 + (((4 + a) ^ (m & 7)) << 4);
    // this lane's two cell rows after half-swap
    const int bA = 4 * (a & 1) + 2 * (a >> 1);   // a=0->0, a=1->4, a=2->2, a=3->6
    const int bB = bA + 1;
    // h write addrs: byte = b*128 + (((j>>3)^b)<<4) + (j&7)*2   (b<8 so b&7=b)
    const int hwaA = bA * 128 + (((jpw >> 3) ^ bA) << 4) + (jpw & 7) * 2;
    const int hwaB = bB * 128 + (((jpw >> 3) ^ bB) << 4) + (jpw & 7) * 2;

    const char* hbytes = (const char*)h_frag;

    float cA = 0.0f, cB = 0.0f, oA = 0.0f, oB = 0.0f;

    __syncthreads();

    for (int t = 0; t < SEQ; ++t) {
        const int rb = (t & 1) << 11;   // read-buffer byte offset

        // ======== gate GEMM (C-in = x*W_ih + bias) ========
        const f16x8 A0 = *(const f16x8*)(hbytes + rb + ra0);
        const f16x8 A1 = *(const f16x8*)(hbytes + rb + ra1);
        float xr[4];
        #pragma unroll
        for (int r = 0; r < 4; ++r) xr[r] = x_lds[4 * a + r][t];   // rows>=8 read 0
        const float wl = wl_lds[t * HID + jpw];

        f32x4 acc[4];
        #pragma unroll
        for (int q = 0; q < 4; ++q) {
            f32x4 ini;
            #pragma unroll
            for (int r = 0; r < 4; ++r) ini[r] = fmaf(xr[r], wihq[q], biasq[q]);
            ini    = __builtin_amdgcn_mfma_f32_16x16x32_f16(A0, Bf[q][0], ini, 0, 0, 0);
            acc[q] = __builtin_amdgcn_mfma_f32_16x16x32_f16(A1, Bf[q][1], acc[q] = ini, 0, 0, 0);
        }

        // ---- half-swap: lanes a>=2 take regs r=2,3 from lane l-32 ----
        float s2[4], s3[4];
        #pragma unroll
        for (int q = 0; q < 4; ++q) {
            s2[q] = __shfl(acc[q][2], l & 31, 64);
            s3[q] = __shfl(acc[q][3], l & 31, 64);
        }
        const bool lo = (a < 2);
        const float gA0 = lo ? acc[0][0] : s2[0];
        const float gA1 = lo ? acc[1][0] : s2[1];
        const float gA2 = lo ? acc[2][0] : s2[2];
        const float gA3 = lo ? acc[3][0] : s2[3];
        const float gB0 = lo ? acc[0][1] : s3[0];
        const float gB1 = lo ? acc[1][1] : s3[1];
        const float gB2 = lo ? acc[2][1] : s3[2];
        const float gB3 = lo ? acc[3][1] : s3[3];

        // ======== pointwise: two cells per thread ========
        {
            const float gi = sigmoid_s(gA0);
            const float gf = sigmoid_s(gA1);
            const float gg = tanh_s2(gA2);
            const float go = sigmoid_s(gA3);
            cA = fmaf(gf, cA, gi * gg);
            const float h = go * tanh_s2((2.0f * LOG2E) * cA);
            oA = fmaf(h, wl, oA);
            *(f16*)((char*)h_frag + (rb ^ 2048) + hwaA) = (f16)h;
        }
        {
            const float gi = sigmoid_s(gB0);
            const float gf = sigmoid_s(gB1);
            const float gg = tanh_s2(gB2);
            const float go = sigmoid_s(gB3);
            cB = fmaf(gf, cB, gi * gg);
            const float h = go * tanh_s2((2.0f * LOG2E) * cB);
            oB = fmaf(h, wl, oB);
            *(f16*)((char*)h_frag + (rb ^ 2048) + hwaB) = (f16)h;
        }

        __syncthreads();   // h(write-buf) complete -> next step reads it
    }

    // ---- reduce over j: 16 lanes (m) in-wave, then 4 waves via LDS ----
    float vA = oA, vB = oB;
    #pragma unroll
    for (int off = 1; off < 16; off <<= 1) {
        vA += __shfl_xor(vA, off, 64);
        vB += __shfl_xor(vB, off, 64);
    }
    if (m == 0) {
        out_part[w][bA] = vA;
        out_part[w][bB] = vB;
    }
    __syncthreads();
    if (tid < BT) {
        out[b0 + tid] = out_part[0][tid] + out_part[1][tid]
                      + out_part[2][tid] + out_part[3][tid] + b_lin[0];
    }
}

extern "C" void kernel_launch(void* const* d_in, const int* in_sizes, int n_in,
                              void* d_out, int out_size, void* d_ws, size_t ws_size,
                              hipStream_t stream) {
    const float* x     = (const float*)d_in[0];
    const float* W_ih  = (const float*)d_in[1];
    const float* W_hh  = (const float*)d_in[2];
    const float* b_ih  = (const float*)d_in[3];
    const float* b_hh  = (const float*)d_in[4];
    const float* W_lin = (const float*)d_in[5];
    const float* b_lin = (const float*)d_in[6];
    float* out = (float*)d_out;

    dim3 grid(NBLK);
    dim3 block(256);
    qlstm_v6<<<grid, block, 0, stream>>>(x, W_ih, W_hh, b_ih, b_hh,
                                         W_lin, b_lin, out);
}